// Round 3
// baseline (399.935 us; speedup 1.0000x reference)
//
#include <hip/hip_runtime.h>

#define BB 512
#define TT 512
#define NTAG 64

// One wave (64 threads) per batch element.
// Lane j owns alpha[j] and E-column j (E = exp(trans)) in registers.
__global__ __launch_bounds__(64) void crf_kernel(
    const float* __restrict__ inputs,   // [B,T,N] f32
    const float* __restrict__ trans,    // [N,N]   f32
    const int*   __restrict__ tags,     // [B,T]   i32
    const int*   __restrict__ lens,     // [B]     i32
    float*       __restrict__ out)      // [B]     f32 (log_likelihood)
{
    const int b = blockIdx.x;
    const int j = threadIdx.x;           // 0..63
    const int len  = lens[b];
    const int last = (len - 1) > 0 ? (len - 1) : 0;

    // ---------------- sequence score (gathers) ----------------
    float sc = 0.f;
    #pragma unroll
    for (int tt = 0; tt < TT / 64; ++tt) {
        const int t = tt * 64 + j;
        if (t < len) {
            const int tg = tags[b * TT + t];
            sc += inputs[(size_t)b * TT * NTAG + (size_t)t * NTAG + tg];
            if (t >= 1) {
                const int tp = tags[b * TT + t - 1];
                sc += trans[tp * NTAG + tg];
            }
        }
    }
    #pragma unroll
    for (int m = 32; m >= 1; m >>= 1) sc += __shfl_xor(sc, m);

    // ---------------- E[:,j] = exp(trans[:,j]) into registers ----------------
    float e[NTAG];
    #pragma unroll
    for (int i = 0; i < NTAG; ++i) e[i] = __expf(trans[i * NTAG + j]);

    // ---------------- forward recurrence ----------------
    const float* emit = inputs + (size_t)b * TT * NTAG;
    float alpha = emit[j];

    // register prefetch ring, distance 3; clamped index is the OOB guard
    // (t+k beyond `last` must not run past the last batch's allocation).
    float pre0 = emit[(size_t)min(1, last) * NTAG + j];
    float pre1 = emit[(size_t)min(2, last) * NTAG + j];
    float pre2 = emit[(size_t)min(3, last) * NTAG + j];

    for (int t = 1; t <= last; ++t) {
        const float cur = pre0;
        pre0 = pre1;
        pre1 = pre2;
        pre2 = emit[(size_t)min(t + 3, last) * NTAG + j];

        // C = any uniform shift; lane-0 alpha is within ~20 of the max
        // (spread bounded by emission spread + transition column spread),
        // so exp stays in f32 range. Avoids a 6-level shfl max-reduce.
        const float C = __uint_as_float(
            __builtin_amdgcn_readfirstlane(__float_as_uint(alpha)));

        const float x = __expf(alpha - C);

        // s_j = sum_i x_i * E[i][j] — 4 partial chains to shorten the
        // dependent-FMA critical path; broadcasts via v_readlane.
        float s0 = 0.f, s1 = 0.f, s2 = 0.f, s3 = 0.f;
        #pragma unroll
        for (int i = 0; i < NTAG; i += 4) {
            s0 = fmaf(__shfl(x, i + 0), e[i + 0], s0);
            s1 = fmaf(__shfl(x, i + 1), e[i + 1], s1);
            s2 = fmaf(__shfl(x, i + 2), e[i + 2], s2);
            s3 = fmaf(__shfl(x, i + 3), e[i + 3], s3);
        }
        const float s = (s0 + s1) + (s2 + s3);

        alpha = cur + C + __logf(s);
    }

    // final logsumexp over lanes (exact max here — runs once)
    float C2 = alpha;
    #pragma unroll
    for (int m = 32; m >= 1; m >>= 1) C2 = fmaxf(C2, __shfl_xor(C2, m));
    float xs = __expf(alpha - C2);
    #pragma unroll
    for (int m = 32; m >= 1; m >>= 1) xs += __shfl_xor(xs, m);
    const float lognorm = C2 + __logf(xs);

    if (j == 0) out[b] = sc - lognorm;
}

__global__ __launch_bounds__(256) void copy_trans_kernel(
    const float* __restrict__ trans, float* __restrict__ out)
{
    const int k = blockIdx.x * 256 + threadIdx.x;
    if (k < NTAG * NTAG) out[k] = trans[k];
}

extern "C" void kernel_launch(void* const* d_in, const int* in_sizes, int n_in,
                              void* d_out, int out_size, void* d_ws, size_t ws_size,
                              hipStream_t stream) {
    const float* inputs = (const float*)d_in[0];
    const float* trans  = (const float*)d_in[1];
    const int*   tags   = (const int*)d_in[2];
    const int*   lens   = (const int*)d_in[3];
    float* out = (float*)d_out;

    crf_kernel<<<BB, 64, 0, stream>>>(inputs, trans, tags, lens, out);
    copy_trans_kernel<<<(NTAG * NTAG + 255) / 256, 256, 0, stream>>>(trans, out + BB);
}

// Round 4
// 274.195 us; speedup vs baseline: 1.4586x; 1.4586x over previous
//
#include <hip/hip_runtime.h>

#define BB 512
#define TT 512
#define NTAG 64

// Broadcast lane `l`'s value of v to all lanes via v_readlane (SGPR dest).
#define BCAST(v, l) __uint_as_float((unsigned)__builtin_amdgcn_readlane((int)__float_as_uint(v), (l)))

// One wave (64 threads) per batch element.
// Lane j owns alpha[j] and E-column j (E = exp(trans)) in registers.
// __launch_bounds__(64, 1): min 1 wave/EU -> VGPR cap 512, so e[64] stays
// in registers (with plain __launch_bounds__(64) the compiler capped at 64
// VGPRs and spilled e[] to scratch -> 320us, VALUBusy 6%).
__global__ __launch_bounds__(64, 1) void crf_kernel(
    const float* __restrict__ inputs,   // [B,T,N] f32
    const float* __restrict__ trans,    // [N,N]   f32
    const int*   __restrict__ tags,     // [B,T]   i32
    const int*   __restrict__ lens,     // [B]     i32
    float*       __restrict__ out)      // [B]     f32 (log_likelihood)
{
    const int b = blockIdx.x;
    const int j = threadIdx.x;           // 0..63
    const int len  = lens[b];
    const int last = (len - 1) > 0 ? (len - 1) : 0;

    // ---------------- sequence score (gathers) ----------------
    float sc = 0.f;
    #pragma unroll
    for (int tt = 0; tt < TT / 64; ++tt) {
        const int t = tt * 64 + j;
        if (t < len) {
            const int tg = tags[b * TT + t];
            sc += inputs[(size_t)b * TT * NTAG + (size_t)t * NTAG + tg];
            if (t >= 1) {
                const int tp = tags[b * TT + t - 1];
                sc += trans[tp * NTAG + tg];
            }
        }
    }
    #pragma unroll
    for (int m = 32; m >= 1; m >>= 1) sc += __shfl_xor(sc, m);

    // ---------------- E[:,j] = exp(trans[:,j]) into registers ----------------
    float e[NTAG];
    #pragma unroll
    for (int i = 0; i < NTAG; ++i) e[i] = __expf(trans[i * NTAG + j]);

    // ---------------- forward recurrence ----------------
    const float* emit = inputs + (size_t)b * TT * NTAG;
    float alpha = emit[j];

    // register prefetch ring, distance 3; clamped index is the OOB guard.
    float pre0 = emit[(size_t)min(1, last) * NTAG + j];
    float pre1 = emit[(size_t)min(2, last) * NTAG + j];
    float pre2 = emit[(size_t)min(3, last) * NTAG + j];

    for (int t = 1; t <= last; ++t) {
        const float cur = pre0;
        pre0 = pre1;
        pre1 = pre2;
        pre2 = emit[(size_t)min(t + 3, last) * NTAG + j];

        // C = any uniform shift; lane-0 alpha is within ~20 of the max
        // (spread bounded by emission + transition column spread), so
        // exp stays comfortably in f32 range.
        const float C = BCAST(alpha, 0);

        const float x = __expf(alpha - C);

        // s_j = sum_i x_i * E[i][j] — v_readlane broadcasts (VALU, no LDS),
        // 4 partial chains to shorten the dependent-FMA critical path.
        float s0 = 0.f, s1 = 0.f, s2 = 0.f, s3 = 0.f;
        #pragma unroll
        for (int i = 0; i < NTAG; i += 4) {
            s0 = fmaf(BCAST(x, i + 0), e[i + 0], s0);
            s1 = fmaf(BCAST(x, i + 1), e[i + 1], s1);
            s2 = fmaf(BCAST(x, i + 2), e[i + 2], s2);
            s3 = fmaf(BCAST(x, i + 3), e[i + 3], s3);
        }
        const float s = (s0 + s1) + (s2 + s3);

        alpha = cur + C + __logf(s);
    }

    // final logsumexp over lanes (exact max here — runs once)
    float C2 = alpha;
    #pragma unroll
    for (int m = 32; m >= 1; m >>= 1) C2 = fmaxf(C2, __shfl_xor(C2, m));
    float xs = __expf(alpha - C2);
    #pragma unroll
    for (int m = 32; m >= 1; m >>= 1) xs += __shfl_xor(xs, m);
    const float lognorm = C2 + __logf(xs);

    if (j == 0) out[b] = sc - lognorm;
}

__global__ __launch_bounds__(256) void copy_trans_kernel(
    const float* __restrict__ trans, float* __restrict__ out)
{
    const int k = blockIdx.x * 256 + threadIdx.x;
    if (k < NTAG * NTAG) out[k] = trans[k];
}

extern "C" void kernel_launch(void* const* d_in, const int* in_sizes, int n_in,
                              void* d_out, int out_size, void* d_ws, size_t ws_size,
                              hipStream_t stream) {
    const float* inputs = (const float*)d_in[0];
    const float* trans  = (const float*)d_in[1];
    const int*   tags   = (const int*)d_in[2];
    const int*   lens   = (const int*)d_in[3];
    float* out = (float*)d_out;

    crf_kernel<<<BB, 64, 0, stream>>>(inputs, trans, tags, lens, out);
    copy_trans_kernel<<<(NTAG * NTAG + 255) / 256, 256, 0, stream>>>(trans, out + BB);
}

// Round 5
// 273.093 us; speedup vs baseline: 1.4645x; 1.0040x over previous
//
#include <hip/hip_runtime.h>

#define BB 512
#define TT 512
#define NTAG 64

// Broadcast lane `l`'s value of v to all lanes via v_readlane (SGPR dest).
#define BCAST(v, l) __uint_as_float((unsigned)__builtin_amdgcn_readlane((int)__float_as_uint(v), (l)))

// 64 individually named E-registers: e0..e63. An indexed array (even with
// all-constant indices after unroll) was sent to scratch by the allocator in
// R3/R4 (VGPR_Count=44, WRITE_SIZE~18MB of spill stores, ~1000cyc/step on
// L2-latency scratch reads). Named scalars cannot spill-by-default.
#define DECL4(a,b,c,d) \
    float e##a = __expf(trans[a * NTAG + j]); \
    float e##b = __expf(trans[b * NTAG + j]); \
    float e##c = __expf(trans[c * NTAG + j]); \
    float e##d = __expf(trans[d * NTAG + j]);

#define FMA4(a,b,c,d) \
    sA = fmaf(BCAST(x, a), e##a, sA); \
    sB = fmaf(BCAST(x, b), e##b, sB); \
    sC = fmaf(BCAST(x, c), e##c, sC); \
    sD = fmaf(BCAST(x, d), e##d, sD);

__global__ __launch_bounds__(64, 1) void crf_kernel(
    const float* __restrict__ inputs,   // [B,T,N] f32
    const float* __restrict__ trans,    // [N,N]   f32
    const int*   __restrict__ tags,     // [B,T]   i32
    const int*   __restrict__ lens,     // [B]     i32
    float*       __restrict__ out)      // [B]     f32 (log_likelihood)
{
    const int b = blockIdx.x;
    const int j = threadIdx.x;           // 0..63
    const int len  = lens[b];
    const int last = (len - 1) > 0 ? (len - 1) : 0;

    // ---------------- sequence score (gathers) ----------------
    float sc = 0.f;
    #pragma unroll
    for (int tt = 0; tt < TT / 64; ++tt) {
        const int t = tt * 64 + j;
        if (t < len) {
            const int tg = tags[b * TT + t];
            sc += inputs[(size_t)b * TT * NTAG + (size_t)t * NTAG + tg];
            if (t >= 1) {
                const int tp = tags[b * TT + t - 1];
                sc += trans[tp * NTAG + tg];
            }
        }
    }
    #pragma unroll
    for (int m = 32; m >= 1; m >>= 1) sc += __shfl_xor(sc, m);

    // ---------------- E[:,j] = exp(trans[:,j]) into NAMED registers --------
    DECL4(0,1,2,3)   DECL4(4,5,6,7)   DECL4(8,9,10,11)  DECL4(12,13,14,15)
    DECL4(16,17,18,19) DECL4(20,21,22,23) DECL4(24,25,26,27) DECL4(28,29,30,31)
    DECL4(32,33,34,35) DECL4(36,37,38,39) DECL4(40,41,42,43) DECL4(44,45,46,47)
    DECL4(48,49,50,51) DECL4(52,53,54,55) DECL4(56,57,58,59) DECL4(60,61,62,63)

    // ---------------- forward recurrence ----------------
    const float* emit = inputs + (size_t)b * TT * NTAG;
    float alpha = emit[j];

    // register prefetch ring, distance 3; clamped index is the OOB guard.
    float pre0 = emit[(size_t)min(1, last) * NTAG + j];
    float pre1 = emit[(size_t)min(2, last) * NTAG + j];
    float pre2 = emit[(size_t)min(3, last) * NTAG + j];

    for (int t = 1; t <= last; ++t) {
        const float cur = pre0;
        pre0 = pre1;
        pre1 = pre2;
        pre2 = emit[(size_t)min(t + 3, last) * NTAG + j];

        // C = any uniform shift; lane-0 alpha is within ~20 of the max
        // (spread bounded by emission + transition column spread), so
        // exp stays comfortably in f32 range.
        const float C = BCAST(alpha, 0);

        const float x = __expf(alpha - C);

        // s_j = sum_i x_i * E[i][j] — v_readlane broadcast (SGPR) feeds
        // v_fmac_f32 directly; 4 partial chains shorten the critical path.
        float sA = 0.f, sB = 0.f, sC = 0.f, sD = 0.f;
        FMA4(0,1,2,3)   FMA4(4,5,6,7)   FMA4(8,9,10,11)  FMA4(12,13,14,15)
        FMA4(16,17,18,19) FMA4(20,21,22,23) FMA4(24,25,26,27) FMA4(28,29,30,31)
        FMA4(32,33,34,35) FMA4(36,37,38,39) FMA4(40,41,42,43) FMA4(44,45,46,47)
        FMA4(48,49,50,51) FMA4(52,53,54,55) FMA4(56,57,58,59) FMA4(60,61,62,63)
        const float s = (sA + sB) + (sC + sD);

        alpha = cur + C + __logf(s);
    }

    // final logsumexp over lanes (exact max here — runs once)
    float C2 = alpha;
    #pragma unroll
    for (int m = 32; m >= 1; m >>= 1) C2 = fmaxf(C2, __shfl_xor(C2, m));
    float xs = __expf(alpha - C2);
    #pragma unroll
    for (int m = 32; m >= 1; m >>= 1) xs += __shfl_xor(xs, m);
    const float lognorm = C2 + __logf(xs);

    if (j == 0) out[b] = sc - lognorm;
}

__global__ __launch_bounds__(256) void copy_trans_kernel(
    const float* __restrict__ trans, float* __restrict__ out)
{
    const int k = blockIdx.x * 256 + threadIdx.x;
    if (k < NTAG * NTAG) out[k] = trans[k];
}

extern "C" void kernel_launch(void* const* d_in, const int* in_sizes, int n_in,
                              void* d_out, int out_size, void* d_ws, size_t ws_size,
                              hipStream_t stream) {
    const float* inputs = (const float*)d_in[0];
    const float* trans  = (const float*)d_in[1];
    const int*   tags   = (const int*)d_in[2];
    const int*   lens   = (const int*)d_in[3];
    float* out = (float*)d_out;

    crf_kernel<<<BB, 64, 0, stream>>>(inputs, trans, tags, lens, out);
    copy_trans_kernel<<<(NTAG * NTAG + 255) / 256, 256, 0, stream>>>(trans, out + BB);
}